// Round 8
// baseline (185.523 us; speedup 1.0000x reference)
//
#include <hip/hip_runtime.h>

// FlexAttention (sliding-window causal + per-head sink), R7 (resubmit after
// infra failure; schedule + exchange re-audited, source unchanged).
// B=2,H=16,S=2048,D=64,W=1024.
//
// R7 changes vs R6:
//  - P round-trip through LDS ELIMINATED: after softmax, lane (c,hl) holds
//    P[q=c][key=(rg&3)+8(rg>>2)+4hl(+32)]; the PV B-frag needs
//    P[q=c][16ks+8hl+j]. Difference is exactly a half-wave quad swap:
//    4x __shfl_xor(32) of packed bf16x4 builds bp[ks] in registers.
//    Removes 8 b64 writes + 4 b128 reads + lgkmcnt per tile from the
//    critical path, and deletes p_lds.
//  - LDS 48->32 KB (2x8K K + 2x8K V double-buffered) -> 5 blocks/CU cap.
//  - Schedule re-cut: 36 bins/bh x exactly 6 tiles (36*6=216), grid 1152
//    = 4.5 blocks/CU (was 3) -> more TLP for the latency-bound regime.
//  - Items 0-2 are single-segment -> direct normalized write; combine
//    handles items 3..15 (<=3 segments each).
// Layouts (m74/m101): A[m=l&31][k=(l>>5)*8+j], B[k=..][n=l&31],
// C/D[row=(rg&3)+8*(rg>>2)+4*(l>>5)][col=l&31].

typedef __bf16 bf16x8 __attribute__((ext_vector_type(8)));
typedef __bf16 bf16x4 __attribute__((ext_vector_type(4)));
typedef float  f32x16 __attribute__((ext_vector_type(16)));

#define NT 256
#define NEG_BIG (-3.0e38f)

// swizzled bf16 index into a [rows][64] bf16 tile (granule = 8 bf16 = 16B)
__device__ __forceinline__ int swz(int row, int gran) {
    return row * 64 + ((gran ^ ((row >> 1) & 7)) << 3);
}

// half-wave exchange of a bf16 quad (lane <-> lane^32)
__device__ __forceinline__ bf16x4 xswap32(bf16x4 v) {
    union { bf16x4 v; int i[2]; } u;
    u.v = v;
    u.i[0] = __shfl_xor(u.i[0], 32, 64);
    u.i[1] = __shfl_xor(u.i[1], 32, 64);
    return u.v;
}

// ---- baked schedule: 36 bins/bh x 6 tiles (coverage hand-verified) ----
// item T: {2,4,6,8,10,12,14,16, 18x8}; sum=216=36*6.
__device__ const int SEG_N[36]     = {2,1,1,2,1,1,1,1,1,2,1,1, 1,1,1,1,1,1,1,1,1,1,1,1,1,1,1,1,1,1,1,1,1,1,1,1};
__device__ const int SEG_IT[36][2] = {
  {0,1},{2,0},{3,0},{3,4},{4,0},{5,0},{5,0},{6,0},{6,0},{6,7},{7,0},{7,0},
  {8,0},{8,0},{8,0},{9,0},{9,0},{9,0},{10,0},{10,0},{10,0},{11,0},{11,0},{11,0},
  {12,0},{12,0},{12,0},{13,0},{13,0},{13,0},{14,0},{14,0},{14,0},{15,0},{15,0},{15,0}};
__device__ const int SEG_J0[36][2] = {
  {0,0},{0,0},{0,0},{6,0},{4,0},{0,0},{6,0},{0,0},{6,0},{12,0},{4,0},{10,0},
  {0,0},{6,0},{12,0},{0,0},{6,0},{12,0},{0,0},{6,0},{12,0},{0,0},{6,0},{12,0},
  {0,0},{6,0},{12,0},{0,0},{6,0},{12,0},{0,0},{6,0},{12,0},{0,0},{6,0},{12,0}};
__device__ const int SEG_J1[36][2] = {
  {2,4},{6,0},{6,0},{8,4},{10,0},{6,0},{12,0},{6,0},{12,0},{14,4},{10,0},{16,0},
  {6,0},{12,0},{18,0},{6,0},{12,0},{18,0},{6,0},{12,0},{18,0},{6,0},{12,0},{18,0},
  {6,0},{12,0},{18,0},{6,0},{12,0},{18,0},{6,0},{12,0},{18,0},{6,0},{12,0},{18,0}};
__device__ const int SEG_SX[36][2] = {
  {0,0},{0,0},{0,0},{1,0},{1,0},{0,0},{1,0},{0,0},{1,0},{2,0},{1,0},{2,0},
  {0,0},{1,0},{2,0},{0,0},{1,0},{2,0},{0,0},{1,0},{2,0},{0,0},{1,0},{2,0},
  {0,0},{1,0},{2,0},{0,0},{1,0},{2,0},{0,0},{1,0},{2,0},{0,0},{1,0},{2,0}};
__device__ const int NSEG_ITEM[16] = {1,1,1,2,2,2,3,3, 3,3,3,3,3,3,3,3};

__global__ __launch_bounds__(NT, 4) void flex_r7_main(
    const float* __restrict__ Q, const float* __restrict__ K,
    const float* __restrict__ V, const float* __restrict__ SINKW,
    const int* __restrict__ SWIN, void* __restrict__ WS,
    float* __restrict__ OUT, const int H, const int S)
{
    const int t    = threadIdx.x;
    const int lane = t & 63;
    const int w    = t >> 6;
    const int c    = lane & 31;
    const int hl   = lane >> 5;
    const int W    = SWIN[0];
    const float scale = 0.125f;

    const int NBH = gridDim.x / 36;
    const int bh  = blockIdx.x / 36;
    const int b36 = blockIdx.x - bh * 36;
    const int h   = bh % H;
    const float sw = SINKW[h];

    __shared__ __align__(16) __bf16 k_lds[2][64 * 64];
    __shared__ __align__(16) __bf16 v_lds[2][64 * 64];

    const size_t basebh = (size_t)bh * S * 64;
    const float4* kp4 = (const float4*)(K + basebh);
    const float4* vp4 = (const float4*)(V + basebh);
    __bf16* O_ws  = (__bf16*)WS;
    float2* ml_ws = (float2*)((char*)WS + (size_t)NBH * 48 * 16384);

    const int dgi = t & 15;   // V staging: dims 4dgi..+3
    const int kgi = t >> 4;   // V staging: keys 4kgi..+3
    float4 kreg[4], vreg[4];

    const int ns = SEG_N[b36];

    // ---- prefetch + stage first tile into buffer 0 ----
    {
        const int it0 = SEG_IT[b36][0];
        const int ktA0 = (2 * it0 - 16 > 0) ? (2 * it0 - 16) : 0;
        const int kt = ktA0 + SEG_J0[b36][0];
        #pragma unroll
        for (int i = 0; i < 4; ++i) kreg[i] = kp4[kt * 1024 + i * NT + t];
        #pragma unroll
        for (int kk = 0; kk < 4; ++kk) vreg[kk] = vp4[kt * 1024 + (4 * kgi + kk) * 16 + dgi];
        #pragma unroll
        for (int i = 0; i < 4; ++i) {
            const int flat = i * NT + t;
            const int key = flat >> 4, dd = flat & 15;
            float4 f = kreg[i];
            bf16x4 b = { (__bf16)f.x, (__bf16)f.y, (__bf16)f.z, (__bf16)f.w };
            *(bf16x4*)&k_lds[0][swz(key, dd >> 1) + (dd & 1) * 4] = b;
        }
        {
            float4 a0 = vreg[0], a1 = vreg[1], a2 = vreg[2], a3 = vreg[3];
            bf16x4 w0 = { (__bf16)a0.x, (__bf16)a1.x, (__bf16)a2.x, (__bf16)a3.x };
            bf16x4 w1 = { (__bf16)a0.y, (__bf16)a1.y, (__bf16)a2.y, (__bf16)a3.y };
            bf16x4 w2 = { (__bf16)a0.z, (__bf16)a1.z, (__bf16)a2.z, (__bf16)a3.z };
            bf16x4 w3 = { (__bf16)a0.w, (__bf16)a1.w, (__bf16)a2.w, (__bf16)a3.w };
            const int gv = kgi >> 1, ov = (kgi & 1) * 4;
            *(bf16x4*)&v_lds[0][swz(4 * dgi + 0, gv) + ov] = w0;
            *(bf16x4*)&v_lds[0][swz(4 * dgi + 1, gv) + ov] = w1;
            *(bf16x4*)&v_lds[0][swz(4 * dgi + 2, gv) + ov] = w2;
            *(bf16x4*)&v_lds[0][swz(4 * dgi + 3, gv) + ov] = w3;
        }
    }

    int par = 0;

    for (int s = 0; s < ns; ++s) {
        const int item = SEG_IT[b36][s];
        const int j0   = SEG_J0[b36][s];
        const int j1   = SEG_J1[b36][s];
        const int sidx = SEG_SX[b36][s];
        const int ktA  = (2 * item - 16 > 0) ? (2 * item - 16) : 0;
        const int qw0  = item * 128 + 32 * w;
        const int qi   = qw0 + c;

        // ---- Q B-fragments (pre-scaled) ----
        bf16x8 bq[4];
        {
            const float4* qp4 = (const float4*)(Q + basebh + (size_t)qi * 64);
            #pragma unroll
            for (int ks = 0; ks < 4; ++ks) {
                float4 f0 = qp4[4 * ks + 2 * hl];
                float4 f1 = qp4[4 * ks + 2 * hl + 1];
                bq[ks][0] = (__bf16)(f0.x * scale); bq[ks][1] = (__bf16)(f0.y * scale);
                bq[ks][2] = (__bf16)(f0.z * scale); bq[ks][3] = (__bf16)(f0.w * scale);
                bq[ks][4] = (__bf16)(f1.x * scale); bq[ks][5] = (__bf16)(f1.y * scale);
                bq[ks][6] = (__bf16)(f1.z * scale); bq[ks][7] = (__bf16)(f1.w * scale);
            }
        }

        float mrun = (sidx == 0) ? sw : NEG_BIG;
        float lrun = (sidx == 0) ? 1.0f : 0.0f;
        f32x16 accO0, accO1;
        #pragma unroll
        for (int i = 0; i < 16; ++i) { accO0[i] = 0.0f; accO1[i] = 0.0f; }

        for (int j = j0; j < j1; ++j) {
            const int k0 = (ktA + j) * 64;

            __syncthreads();   // buf[par] staged & visible; prev compute done

            // ---- prefetch next tile EARLY (consumed after compute) ----
            int nkt = -1;
            if (j + 1 < j1) nkt = ktA + j + 1;
            else if (s + 1 < ns) {
                const int it2 = SEG_IT[b36][s + 1];
                const int ktA2 = (2 * it2 - 16 > 0) ? (2 * it2 - 16) : 0;
                nkt = ktA2 + SEG_J0[b36][s + 1];
            }
            if (nkt >= 0) {
                #pragma unroll
                for (int i = 0; i < 4; ++i) kreg[i] = kp4[nkt * 1024 + i * NT + t];
                #pragma unroll
                for (int kk = 0; kk < 4; ++kk) vreg[kk] = vp4[nkt * 1024 + (4 * kgi + kk) * 16 + dgi];
            }

            // ---- S^T = K · Q^T ----
            const __bf16* kb = k_lds[par];
            const __bf16* vb = v_lds[par];
            f32x16 accS0, accS1;
            #pragma unroll
            for (int i = 0; i < 16; ++i) { accS0[i] = 0.0f; accS1[i] = 0.0f; }
            #pragma unroll
            for (int ks = 0; ks < 4; ++ks) {
                bf16x8 ka0 = *(const bf16x8*)&kb[swz(c,      2 * ks + hl)];
                bf16x8 ka1 = *(const bf16x8*)&kb[swz(32 + c, 2 * ks + hl)];
                accS0 = __builtin_amdgcn_mfma_f32_32x32x16_bf16(ka0, bq[ks], accS0, 0, 0, 0);
                accS1 = __builtin_amdgcn_mfma_f32_32x32x16_bf16(ka1, bq[ks], accS1, 0, 0, 0);
            }

            // ---- mask (wave-uniform skip when interior) ----
            const bool interior = (k0 + 63 <= qw0) && (qw0 + 31 - k0 <= W);
            if (!interior) {
                #pragma unroll
                for (int rg = 0; rg < 16; ++rg) {
                    const int kb2 = (rg & 3) + 8 * (rg >> 2) + 4 * hl;
                    const int ki0 = k0 + kb2, ki1 = k0 + 32 + kb2;
                    if (!((ki0 <= qi) && (qi - ki0 <= W))) accS0[rg] = -1e30f;
                    if (!((ki1 <= qi) && (qi - ki1 <= W))) accS1[rg] = -1e30f;
                }
            }

            // ---- online softmax ----
            float mx = accS0[0];
            #pragma unroll
            for (int i = 1; i < 16; ++i) mx = fmaxf(mx, accS0[i]);
            #pragma unroll
            for (int i = 0; i < 16; ++i) mx = fmaxf(mx, accS1[i]);
            mx = fmaxf(mx, __shfl_xor(mx, 32, 64));
            const float mnew  = fmaxf(mrun, mx);
            const float alpha = __expf(mrun - mnew);
            float ps = 0.0f;
            #pragma unroll
            for (int i = 0; i < 16; ++i) { float p = __expf(accS0[i] - mnew); accS0[i] = p; ps += p; }
            #pragma unroll
            for (int i = 0; i < 16; ++i) { float p = __expf(accS1[i] - mnew); accS1[i] = p; ps += p; }
            ps += __shfl_xor(ps, 32, 64);
            lrun = lrun * alpha + ps;
            mrun = mnew;
            #pragma unroll
            for (int i = 0; i < 16; ++i) { accO0[i] *= alpha; accO1[i] *= alpha; }

            // ---- P -> B-fragments IN REGISTERS (half-wave quad exchange) ----
            bf16x4 qA = { (__bf16)accS0[0],  (__bf16)accS0[1],  (__bf16)accS0[2],  (__bf16)accS0[3]  };
            bf16x4 qB = { (__bf16)accS0[4],  (__bf16)accS0[5],  (__bf16)accS0[6],  (__bf16)accS0[7]  };
            bf16x4 qC = { (__bf16)accS0[8],  (__bf16)accS0[9],  (__bf16)accS0[10], (__bf16)accS0[11] };
            bf16x4 qD = { (__bf16)accS0[12], (__bf16)accS0[13], (__bf16)accS0[14], (__bf16)accS0[15] };
            bf16x4 qE = { (__bf16)accS1[0],  (__bf16)accS1[1],  (__bf16)accS1[2],  (__bf16)accS1[3]  };
            bf16x4 qF = { (__bf16)accS1[4],  (__bf16)accS1[5],  (__bf16)accS1[6],  (__bf16)accS1[7]  };
            bf16x4 qG = { (__bf16)accS1[8],  (__bf16)accS1[9],  (__bf16)accS1[10], (__bf16)accS1[11] };
            bf16x4 qH = { (__bf16)accS1[12], (__bf16)accS1[13], (__bf16)accS1[14], (__bf16)accS1[15] };
            bf16x4 r0 = xswap32(hl ? qA : qB);
            bf16x4 r1 = xswap32(hl ? qC : qD);
            bf16x4 r2 = xswap32(hl ? qE : qF);
            bf16x4 r3 = xswap32(hl ? qG : qH);
            bf16x4 lo0 = hl ? r0 : qA, hi0 = hl ? qB : r0;
            bf16x4 lo1 = hl ? r1 : qC, hi1 = hl ? qD : r1;
            bf16x4 lo2 = hl ? r2 : qE, hi2 = hl ? qF : r2;
            bf16x4 lo3 = hl ? r3 : qG, hi3 = hl ? qH : r3;
            bf16x8 bp[4];
            #pragma unroll
            for (int e = 0; e < 4; ++e) {
                bp[0][e] = lo0[e]; bp[0][4+e] = hi0[e];
                bp[1][e] = lo1[e]; bp[1][4+e] = hi1[e];
                bp[2][e] = lo2[e]; bp[2][4+e] = hi2[e];
                bp[3][e] = lo3[e]; bp[3][4+e] = hi3[e];
            }

            // ---- O^T += V^T · P^T ----
            #pragma unroll
            for (int ks = 0; ks < 4; ++ks) {
                bf16x8 va0 = *(const bf16x8*)&vb[swz(c,      2 * ks + hl)];
                bf16x8 va1 = *(const bf16x8*)&vb[swz(32 + c, 2 * ks + hl)];
                accO0 = __builtin_amdgcn_mfma_f32_32x32x16_bf16(va0, bp[ks], accO0, 0, 0, 0);
                accO1 = __builtin_amdgcn_mfma_f32_32x32x16_bf16(va1, bp[ks], accO1, 0, 0, 0);
            }

            // ---- stage next tile into the other buffer (consumes prefetch) ----
            if (nkt >= 0) {
                const int np = par ^ 1;
                #pragma unroll
                for (int i = 0; i < 4; ++i) {
                    const int flat = i * NT + t;
                    const int key = flat >> 4, dd = flat & 15;
                    float4 f = kreg[i];
                    bf16x4 b = { (__bf16)f.x, (__bf16)f.y, (__bf16)f.z, (__bf16)f.w };
                    *(bf16x4*)&k_lds[np][swz(key, dd >> 1) + (dd & 1) * 4] = b;
                }
                float4 a0 = vreg[0], a1 = vreg[1], a2 = vreg[2], a3 = vreg[3];
                bf16x4 w0 = { (__bf16)a0.x, (__bf16)a1.x, (__bf16)a2.x, (__bf16)a3.x };
                bf16x4 w1 = { (__bf16)a0.y, (__bf16)a1.y, (__bf16)a2.y, (__bf16)a3.y };
                bf16x4 w2 = { (__bf16)a0.z, (__bf16)a1.z, (__bf16)a2.z, (__bf16)a3.z };
                bf16x4 w3 = { (__bf16)a0.w, (__bf16)a1.w, (__bf16)a2.w, (__bf16)a3.w };
                const int gv = kgi >> 1, ov = (kgi & 1) * 4;
                *(bf16x4*)&v_lds[np][swz(4 * dgi + 0, gv) + ov] = w0;
                *(bf16x4*)&v_lds[np][swz(4 * dgi + 1, gv) + ov] = w1;
                *(bf16x4*)&v_lds[np][swz(4 * dgi + 2, gv) + ov] = w2;
                *(bf16x4*)&v_lds[np][swz(4 * dgi + 3, gv) + ov] = w3;
            }
            par ^= 1;
        }

        if (item < 3) {
            // ---- single-segment item: write normalized output directly ----
            const float inv = 1.0f / lrun;
            float* ob = OUT + basebh + (size_t)qi * 64;
            #pragma unroll
            for (int rg = 0; rg < 4; ++rg) {
                float4 f0 = { accO0[4*rg+0]*inv, accO0[4*rg+1]*inv,
                              accO0[4*rg+2]*inv, accO0[4*rg+3]*inv };
                float4 f1 = { accO1[4*rg+0]*inv, accO1[4*rg+1]*inv,
                              accO1[4*rg+2]*inv, accO1[4*rg+3]*inv };
                *(float4*)&ob[     8 * rg + 4 * hl] = f0;
                *(float4*)&ob[32 + 8 * rg + 4 * hl] = f1;
            }
        } else {
            // ---- write partials ----
            const int slot = (bh * 16 + item) * 3 + sidx;
            const int qrel = 32 * w + c;
            if (hl == 0) ml_ws[(size_t)slot * 128 + qrel] = make_float2(mrun, lrun);
            __bf16* Os = O_ws + (size_t)slot * 8192 + (size_t)qrel * 64;
            #pragma unroll
            for (int qd = 0; qd < 4; ++qd) {
                const int d0 = 8 * qd + 4 * hl;
                bf16x4 b0 = { (__bf16)accO0[4*qd+0], (__bf16)accO0[4*qd+1],
                              (__bf16)accO0[4*qd+2], (__bf16)accO0[4*qd+3] };
                bf16x4 b1 = { (__bf16)accO1[4*qd+0], (__bf16)accO1[4*qd+1],
                              (__bf16)accO1[4*qd+2], (__bf16)accO1[4*qd+3] };
                *(bf16x4*)&Os[d0]      = b0;
                *(bf16x4*)&Os[32 + d0] = b1;
            }
        }
    }
}

__global__ __launch_bounds__(256) void flex_r7_combine(
    const void* __restrict__ WS, float* __restrict__ OUT, const int H, const int S)
{
    const int NBH  = gridDim.x / 13;
    const int bi   = blockIdx.x;
    const int bh   = bi / 13;
    const int item = 3 + (bi - bh * 13);      // items 3..15 (multi-segment)
    const int ns   = NSEG_ITEM[item];
    const int t    = threadIdx.x;
    const int q    = t >> 1;
    const int half = t & 1;

    const __bf16* O_ws = (const __bf16*)WS;
    const float2* ml_ws = (const float2*)((const char*)WS + (size_t)NBH * 48 * 16384);
    const int base = (bh * 16 + item) * 3;

    float m[3], lv[3], a[3];
    float mst = NEG_BIG;
    for (int s = 0; s < ns; ++s) {
        float2 e = ml_ws[(size_t)(base + s) * 128 + q];
        m[s] = e.x; lv[s] = e.y;
        mst = fmaxf(mst, m[s]);
    }
    float lst = 0.0f;
    for (int s = 0; s < ns; ++s) { a[s] = __expf(m[s] - mst); lst += a[s] * lv[s]; }
    const float inv = 1.0f / lst;

    float acc[32];
    #pragma unroll
    for (int i = 0; i < 32; ++i) acc[i] = 0.0f;
    for (int s = 0; s < ns; ++s) {
        const __bf16* Os = O_ws + (size_t)(base + s) * 8192 + (size_t)q * 64 + 32 * half;
        const float as = a[s];
        #pragma unroll
        for (int v8 = 0; v8 < 4; ++v8) {
            bf16x8 o = *(const bf16x8*)&Os[8 * v8];
            #pragma unroll
            for (int jj = 0; jj < 8; ++jj) acc[8 * v8 + jj] += as * (float)o[jj];
        }
    }

    float* dst = OUT + (size_t)bh * S * 64 + (size_t)(item * 128 + q) * 64 + 32 * half;
    #pragma unroll
    for (int v4 = 0; v4 < 8; ++v4) {
        float4 f = { acc[4*v4+0] * inv, acc[4*v4+1] * inv,
                     acc[4*v4+2] * inv, acc[4*v4+3] * inv };
        *(float4*)&dst[4 * v4] = f;
    }
}

extern "C" void kernel_launch(void* const* d_in, const int* in_sizes, int n_in,
                              void* d_out, int out_size, void* d_ws, size_t ws_size,
                              hipStream_t stream) {
    const float* q     = (const float*)d_in[0];
    const float* k     = (const float*)d_in[1];
    const float* v     = (const float*)d_in[2];
    const float* sinkw = (const float*)d_in[3];
    const int*   swin  = (const int*)d_in[4];
    float* out = (float*)d_out;

    const int H = in_sizes[3];                   // 16
    const int S = 2048;
    const int B = in_sizes[0] / (H * S * 64);    // 2
    const int NBH = B * H;                       // 32

    flex_r7_main<<<dim3(NBH * 36), NT, 0, stream>>>(q, k, v, sinkw, swin, d_ws, out, H, S);
    flex_r7_combine<<<dim3(NBH * 13), 256, 0, stream>>>(d_ws, out, H, S);
}

// Round 9
// 139.209 us; speedup vs baseline: 1.3327x; 1.3327x over previous
//
#include <hip/hip_runtime.h>

// FlexAttention (sliding-window causal + per-head sink), R9.
// B=2,H=16,S=2048,D=64,W=1024.
//
// R9 = R6 structure + R7's in-register P exchange, WITHOUT R7's spill:
//  - __launch_bounds__(256, 3): R7's (,4) capped regs at ~128 < ~150 live
//    -> spill -> 110 MB scratch traffic (WRITE_SIZE 24->127 MB, VGPR=64).
//    Bound 3 gives ~170: no spill (R6 compiled 84 VGPR under it).
//  - 24-bin x 9-tile schedule (grid 768 = exactly 3 blocks/CU, flat);
//    1152 blocks at 3-resident would run a half-empty second round.
//  - P->PV B-frag via half-wave quad exchange (4x shfl_xor(32)), no p_lds,
//    no lgkmcnt sync point in the P path. LDS 32 KB (2x8K K + 2x8K V).
//  - One barrier/tile; prefetch issued right after barrier, staged after
//    compute (nothing in flight when the barrier's vmcnt(0) drain hits).
// Layouts (m74/m101): A[m=l&31][k=(l>>5)*8+j], B[k=..][n=l&31],
// C/D[row=(rg&3)+8*(rg>>2)+4*(l>>5)][col=l&31].

typedef __bf16 bf16x8 __attribute__((ext_vector_type(8)));
typedef __bf16 bf16x4 __attribute__((ext_vector_type(4)));
typedef float  f32x16 __attribute__((ext_vector_type(16)));

#define NT 256
#define NEG_BIG (-3.0e38f)

__device__ __forceinline__ int swz(int row, int gran) {
    return row * 64 + ((gran ^ ((row >> 1) & 7)) << 3);
}

__device__ __forceinline__ bf16x4 xswap32(bf16x4 v) {
    union { bf16x4 v; int i[2]; } u;
    u.v = v;
    u.i[0] = __shfl_xor(u.i[0], 32, 64);
    u.i[1] = __shfl_xor(u.i[1], 32, 64);
    return u.v;
}

// ---- baked schedule (R5/R6, verified): 24 bins/bh x exactly 9 tiles ----
__device__ const int SEG_N[24] = {3,2,2,2,2,1,2,1, 1,1,1,1,1,1,1,1, 1,1,1,1,1,1,1,1};
__device__ const int SEG_IT[24][3] = {
  {0,1,2},{2,3,0},{3,4,0},{4,5,0},{5,6,0},{6,0,0},{6,7,0},{7,0,0},
  {8,0,0},{8,0,0},{9,0,0},{9,0,0},{10,0,0},{10,0,0},{11,0,0},{11,0,0},
  {12,0,0},{12,0,0},{13,0,0},{13,0,0},{14,0,0},{14,0,0},{15,0,0},{15,0,0}};
__device__ const int SEG_J0[24][3] = {
  {0,0,0},{3,0,0},{6,0,0},{7,0,0},{6,0,0},{3,0,0},{12,0,0},{7,0,0},
  {0,0,0},{9,0,0},{0,0,0},{9,0,0},{0,0,0},{9,0,0},{0,0,0},{9,0,0},
  {0,0,0},{9,0,0},{0,0,0},{9,0,0},{0,0,0},{9,0,0},{0,0,0},{9,0,0}};
__device__ const int SEG_J1[24][3] = {
  {2,4,3},{6,6,0},{8,7,0},{10,6,0},{12,3,0},{12,0,0},{14,7,0},{16,0,0},
  {9,0,0},{18,0,0},{9,0,0},{18,0,0},{9,0,0},{18,0,0},{9,0,0},{18,0,0},
  {9,0,0},{18,0,0},{9,0,0},{18,0,0},{9,0,0},{18,0,0},{9,0,0},{18,0,0}};
__device__ const int SEG_SX[24][3] = {
  {0,0,0},{1,0,0},{1,0,0},{1,0,0},{1,0,0},{1,0,0},{2,0,0},{1,0,0},
  {0,0,0},{1,0,0},{0,0,0},{1,0,0},{0,0,0},{1,0,0},{0,0,0},{1,0,0},
  {0,0,0},{1,0,0},{0,0,0},{1,0,0},{0,0,0},{1,0,0},{0,0,0},{1,0,0}};
__device__ const int NSEG_ITEM[16] = {1,1,2,2,2,2,3,2, 2,2,2,2,2,2,2,2};

__global__ __launch_bounds__(NT, 3) void flex_r9_main(
    const float* __restrict__ Q, const float* __restrict__ K,
    const float* __restrict__ V, const float* __restrict__ SINKW,
    const int* __restrict__ SWIN, void* __restrict__ WS,
    float* __restrict__ OUT, const int H, const int S)
{
    const int t    = threadIdx.x;
    const int lane = t & 63;
    const int w    = t >> 6;
    const int c    = lane & 31;
    const int hl   = lane >> 5;
    const int W    = SWIN[0];
    const float scale = 0.125f;

    const int NBH = gridDim.x / 24;
    const int bh  = blockIdx.x / 24;
    const int b24 = blockIdx.x - bh * 24;
    const int h   = bh % H;
    const float sw = SINKW[h];

    __shared__ __align__(16) __bf16 k_lds[2][64 * 64];
    __shared__ __align__(16) __bf16 v_lds[2][64 * 64];

    const size_t basebh = (size_t)bh * S * 64;
    const float4* kp4 = (const float4*)(K + basebh);
    const float4* vp4 = (const float4*)(V + basebh);
    __bf16* O_ws  = (__bf16*)WS;
    float2* ml_ws = (float2*)((char*)WS + (size_t)NBH * 48 * 16384);

    const int dgi = t & 15;   // V staging: dims 4dgi..+3
    const int kgi = t >> 4;   // V staging: keys 4kgi..+3
    float4 kreg[4], vreg[4];

    const int ns = SEG_N[b24];

    // ---- prefetch + stage first tile into buffer 0 ----
    {
        const int it0 = SEG_IT[b24][0];
        const int ktA0 = (2 * it0 - 16 > 0) ? (2 * it0 - 16) : 0;
        const int kt = ktA0 + SEG_J0[b24][0];
        #pragma unroll
        for (int i = 0; i < 4; ++i) kreg[i] = kp4[kt * 1024 + i * NT + t];
        #pragma unroll
        for (int kk = 0; kk < 4; ++kk) vreg[kk] = vp4[kt * 1024 + (4 * kgi + kk) * 16 + dgi];
        #pragma unroll
        for (int i = 0; i < 4; ++i) {
            const int flat = i * NT + t;
            const int key = flat >> 4, dd = flat & 15;
            float4 f = kreg[i];
            bf16x4 b = { (__bf16)f.x, (__bf16)f.y, (__bf16)f.z, (__bf16)f.w };
            *(bf16x4*)&k_lds[0][swz(key, dd >> 1) + (dd & 1) * 4] = b;
        }
        {
            float4 a0 = vreg[0], a1 = vreg[1], a2 = vreg[2], a3 = vreg[3];
            bf16x4 w0 = { (__bf16)a0.x, (__bf16)a1.x, (__bf16)a2.x, (__bf16)a3.x };
            bf16x4 w1 = { (__bf16)a0.y, (__bf16)a1.y, (__bf16)a2.y, (__bf16)a3.y };
            bf16x4 w2 = { (__bf16)a0.z, (__bf16)a1.z, (__bf16)a2.z, (__bf16)a3.z };
            bf16x4 w3 = { (__bf16)a0.w, (__bf16)a1.w, (__bf16)a2.w, (__bf16)a3.w };
            const int gv = kgi >> 1, ov = (kgi & 1) * 4;
            *(bf16x4*)&v_lds[0][swz(4 * dgi + 0, gv) + ov] = w0;
            *(bf16x4*)&v_lds[0][swz(4 * dgi + 1, gv) + ov] = w1;
            *(bf16x4*)&v_lds[0][swz(4 * dgi + 2, gv) + ov] = w2;
            *(bf16x4*)&v_lds[0][swz(4 * dgi + 3, gv) + ov] = w3;
        }
    }

    int par = 0;

    for (int s = 0; s < ns; ++s) {
        const int item = SEG_IT[b24][s];
        const int j0   = SEG_J0[b24][s];
        const int j1   = SEG_J1[b24][s];
        const int sidx = SEG_SX[b24][s];
        const int ktA  = (2 * item - 16 > 0) ? (2 * item - 16) : 0;
        const int qw0  = item * 128 + 32 * w;
        const int qi   = qw0 + c;

        // ---- Q B-fragments (pre-scaled) ----
        bf16x8 bq[4];
        {
            const float4* qp4 = (const float4*)(Q + basebh + (size_t)qi * 64);
            #pragma unroll
            for (int ks = 0; ks < 4; ++ks) {
                float4 f0 = qp4[4 * ks + 2 * hl];
                float4 f1 = qp4[4 * ks + 2 * hl + 1];
                bq[ks][0] = (__bf16)(f0.x * scale); bq[ks][1] = (__bf16)(f0.y * scale);
                bq[ks][2] = (__bf16)(f0.z * scale); bq[ks][3] = (__bf16)(f0.w * scale);
                bq[ks][4] = (__bf16)(f1.x * scale); bq[ks][5] = (__bf16)(f1.y * scale);
                bq[ks][6] = (__bf16)(f1.z * scale); bq[ks][7] = (__bf16)(f1.w * scale);
            }
        }

        float mrun = (sidx == 0) ? sw : NEG_BIG;
        float lrun = (sidx == 0) ? 1.0f : 0.0f;
        f32x16 accO0, accO1;
        #pragma unroll
        for (int i = 0; i < 16; ++i) { accO0[i] = 0.0f; accO1[i] = 0.0f; }

        for (int j = j0; j < j1; ++j) {
            const int k0 = (ktA + j) * 64;

            __syncthreads();   // buf[par] staged & visible; prev compute done

            // ---- prefetch next tile EARLY (consumed after compute) ----
            int nkt = -1;
            if (j + 1 < j1) nkt = ktA + j + 1;
            else if (s + 1 < ns) {
                const int it2 = SEG_IT[b24][s + 1];
                const int ktA2 = (2 * it2 - 16 > 0) ? (2 * it2 - 16) : 0;
                nkt = ktA2 + SEG_J0[b24][s + 1];
            }
            if (nkt >= 0) {
                #pragma unroll
                for (int i = 0; i < 4; ++i) kreg[i] = kp4[nkt * 1024 + i * NT + t];
                #pragma unroll
                for (int kk = 0; kk < 4; ++kk) vreg[kk] = vp4[nkt * 1024 + (4 * kgi + kk) * 16 + dgi];
            }

            // ---- S^T = K · Q^T ----
            const __bf16* kb = k_lds[par];
            const __bf16* vb = v_lds[par];
            f32x16 accS0, accS1;
            #pragma unroll
            for (int i = 0; i < 16; ++i) { accS0[i] = 0.0f; accS1[i] = 0.0f; }
            #pragma unroll
            for (int ks = 0; ks < 4; ++ks) {
                bf16x8 ka0 = *(const bf16x8*)&kb[swz(c,      2 * ks + hl)];
                bf16x8 ka1 = *(const bf16x8*)&kb[swz(32 + c, 2 * ks + hl)];
                accS0 = __builtin_amdgcn_mfma_f32_32x32x16_bf16(ka0, bq[ks], accS0, 0, 0, 0);
                accS1 = __builtin_amdgcn_mfma_f32_32x32x16_bf16(ka1, bq[ks], accS1, 0, 0, 0);
            }

            // ---- mask (wave-uniform skip when interior) ----
            const bool interior = (k0 + 63 <= qw0) && (qw0 + 31 - k0 <= W);
            if (!interior) {
                #pragma unroll
                for (int rg = 0; rg < 16; ++rg) {
                    const int kb2 = (rg & 3) + 8 * (rg >> 2) + 4 * hl;
                    const int ki0 = k0 + kb2, ki1 = k0 + 32 + kb2;
                    if (!((ki0 <= qi) && (qi - ki0 <= W))) accS0[rg] = -1e30f;
                    if (!((ki1 <= qi) && (qi - ki1 <= W))) accS1[rg] = -1e30f;
                }
            }

            // ---- online softmax ----
            float mx = accS0[0];
            #pragma unroll
            for (int i = 1; i < 16; ++i) mx = fmaxf(mx, accS0[i]);
            #pragma unroll
            for (int i = 0; i < 16; ++i) mx = fmaxf(mx, accS1[i]);
            mx = fmaxf(mx, __shfl_xor(mx, 32, 64));
            const float mnew  = fmaxf(mrun, mx);
            const float alpha = __expf(mrun - mnew);
            float ps = 0.0f;
            #pragma unroll
            for (int i = 0; i < 16; ++i) { float p = __expf(accS0[i] - mnew); accS0[i] = p; ps += p; }
            #pragma unroll
            for (int i = 0; i < 16; ++i) { float p = __expf(accS1[i] - mnew); accS1[i] = p; ps += p; }
            ps += __shfl_xor(ps, 32, 64);
            lrun = lrun * alpha + ps;
            mrun = mnew;
            #pragma unroll
            for (int i = 0; i < 16; ++i) { accO0[i] *= alpha; accO1[i] *= alpha; }

            // ---- P -> B-fragments IN REGISTERS (half-wave quad exchange) ----
            bf16x4 qA = { (__bf16)accS0[0],  (__bf16)accS0[1],  (__bf16)accS0[2],  (__bf16)accS0[3]  };
            bf16x4 qB = { (__bf16)accS0[4],  (__bf16)accS0[5],  (__bf16)accS0[6],  (__bf16)accS0[7]  };
            bf16x4 qC = { (__bf16)accS0[8],  (__bf16)accS0[9],  (__bf16)accS0[10], (__bf16)accS0[11] };
            bf16x4 qD = { (__bf16)accS0[12], (__bf16)accS0[13], (__bf16)accS0[14], (__bf16)accS0[15] };
            bf16x4 qE = { (__bf16)accS1[0],  (__bf16)accS1[1],  (__bf16)accS1[2],  (__bf16)accS1[3]  };
            bf16x4 qF = { (__bf16)accS1[4],  (__bf16)accS1[5],  (__bf16)accS1[6],  (__bf16)accS1[7]  };
            bf16x4 qG = { (__bf16)accS1[8],  (__bf16)accS1[9],  (__bf16)accS1[10], (__bf16)accS1[11] };
            bf16x4 qH = { (__bf16)accS1[12], (__bf16)accS1[13], (__bf16)accS1[14], (__bf16)accS1[15] };
            bf16x4 r0 = xswap32(hl ? qA : qB);
            bf16x4 r1 = xswap32(hl ? qC : qD);
            bf16x4 r2 = xswap32(hl ? qE : qF);
            bf16x4 r3 = xswap32(hl ? qG : qH);
            bf16x4 lo0 = hl ? r0 : qA, hi0 = hl ? qB : r0;
            bf16x4 lo1 = hl ? r1 : qC, hi1 = hl ? qD : r1;
            bf16x4 lo2 = hl ? r2 : qE, hi2 = hl ? qF : r2;
            bf16x4 lo3 = hl ? r3 : qG, hi3 = hl ? qH : r3;
            bf16x8 bp[4];
            #pragma unroll
            for (int e = 0; e < 4; ++e) {
                bp[0][e] = lo0[e]; bp[0][4+e] = hi0[e];
                bp[1][e] = lo1[e]; bp[1][4+e] = hi1[e];
                bp[2][e] = lo2[e]; bp[2][4+e] = hi2[e];
                bp[3][e] = lo3[e]; bp[3][4+e] = hi3[e];
            }

            // ---- O^T += V^T · P^T ----
            #pragma unroll
            for (int ks = 0; ks < 4; ++ks) {
                bf16x8 va0 = *(const bf16x8*)&vb[swz(c,      2 * ks + hl)];
                bf16x8 va1 = *(const bf16x8*)&vb[swz(32 + c, 2 * ks + hl)];
                accO0 = __builtin_amdgcn_mfma_f32_32x32x16_bf16(va0, bp[ks], accO0, 0, 0, 0);
                accO1 = __builtin_amdgcn_mfma_f32_32x32x16_bf16(va1, bp[ks], accO1, 0, 0, 0);
            }

            // ---- stage next tile into the other buffer (consumes prefetch) ----
            if (nkt >= 0) {
                const int np = par ^ 1;
                #pragma unroll
                for (int i = 0; i < 4; ++i) {
                    const int flat = i * NT + t;
                    const int key = flat >> 4, dd = flat & 15;
                    float4 f = kreg[i];
                    bf16x4 b = { (__bf16)f.x, (__bf16)f.y, (__bf16)f.z, (__bf16)f.w };
                    *(bf16x4*)&k_lds[np][swz(key, dd >> 1) + (dd & 1) * 4] = b;
                }
                float4 a0 = vreg[0], a1 = vreg[1], a2 = vreg[2], a3 = vreg[3];
                bf16x4 w0 = { (__bf16)a0.x, (__bf16)a1.x, (__bf16)a2.x, (__bf16)a3.x };
                bf16x4 w1 = { (__bf16)a0.y, (__bf16)a1.y, (__bf16)a2.y, (__bf16)a3.y };
                bf16x4 w2 = { (__bf16)a0.z, (__bf16)a1.z, (__bf16)a2.z, (__bf16)a3.z };
                bf16x4 w3 = { (__bf16)a0.w, (__bf16)a1.w, (__bf16)a2.w, (__bf16)a3.w };
                const int gv = kgi >> 1, ov = (kgi & 1) * 4;
                *(bf16x4*)&v_lds[np][swz(4 * dgi + 0, gv) + ov] = w0;
                *(bf16x4*)&v_lds[np][swz(4 * dgi + 1, gv) + ov] = w1;
                *(bf16x4*)&v_lds[np][swz(4 * dgi + 2, gv) + ov] = w2;
                *(bf16x4*)&v_lds[np][swz(4 * dgi + 3, gv) + ov] = w3;
            }
            par ^= 1;
        }

        if (item < 2) {
            // ---- single-segment item: write normalized output directly ----
            const float inv = 1.0f / lrun;
            float* ob = OUT + basebh + (size_t)qi * 64;
            #pragma unroll
            for (int rg = 0; rg < 4; ++rg) {
                float4 f0 = { accO0[4*rg+0]*inv, accO0[4*rg+1]*inv,
                              accO0[4*rg+2]*inv, accO0[4*rg+3]*inv };
                float4 f1 = { accO1[4*rg+0]*inv, accO1[4*rg+1]*inv,
                              accO1[4*rg+2]*inv, accO1[4*rg+3]*inv };
                *(float4*)&ob[     8 * rg + 4 * hl] = f0;
                *(float4*)&ob[32 + 8 * rg + 4 * hl] = f1;
            }
        } else {
            // ---- write partials ----
            const int slot = (bh * 16 + item) * 3 + sidx;
            const int qrel = 32 * w + c;
            if (hl == 0) ml_ws[(size_t)slot * 128 + qrel] = make_float2(mrun, lrun);
            __bf16* Os = O_ws + (size_t)slot * 8192 + (size_t)qrel * 64;
            #pragma unroll
            for (int qd = 0; qd < 4; ++qd) {
                const int d0 = 8 * qd + 4 * hl;
                bf16x4 b0 = { (__bf16)accO0[4*qd+0], (__bf16)accO0[4*qd+1],
                              (__bf16)accO0[4*qd+2], (__bf16)accO0[4*qd+3] };
                bf16x4 b1 = { (__bf16)accO1[4*qd+0], (__bf16)accO1[4*qd+1],
                              (__bf16)accO1[4*qd+2], (__bf16)accO1[4*qd+3] };
                *(bf16x4*)&Os[d0]      = b0;
                *(bf16x4*)&Os[32 + d0] = b1;
            }
        }
    }
}

__global__ __launch_bounds__(256) void flex_r9_combine(
    const void* __restrict__ WS, float* __restrict__ OUT, const int H, const int S)
{
    const int NBH  = gridDim.x / 14;
    const int bi   = blockIdx.x;
    const int bh   = bi / 14;
    const int item = 2 + (bi - bh * 14);      // items 2..15 (multi-segment)
    const int ns   = NSEG_ITEM[item];
    const int t    = threadIdx.x;
    const int q    = t >> 1;
    const int half = t & 1;

    const __bf16* O_ws = (const __bf16*)WS;
    const float2* ml_ws = (const float2*)((const char*)WS + (size_t)NBH * 48 * 16384);
    const int base = (bh * 16 + item) * 3;

    float m[3], lv[3], a[3];
    float mst = NEG_BIG;
    for (int s = 0; s < ns; ++s) {
        float2 e = ml_ws[(size_t)(base + s) * 128 + q];
        m[s] = e.x; lv[s] = e.y;
        mst = fmaxf(mst, m[s]);
    }
    float lst = 0.0f;
    for (int s = 0; s < ns; ++s) { a[s] = __expf(m[s] - mst); lst += a[s] * lv[s]; }
    const float inv = 1.0f / lst;

    float acc[32];
    #pragma unroll
    for (int i = 0; i < 32; ++i) acc[i] = 0.0f;
    for (int s = 0; s < ns; ++s) {
        const __bf16* Os = O_ws + (size_t)(base + s) * 8192 + (size_t)q * 64 + 32 * half;
        const float as = a[s];
        #pragma unroll
        for (int v8 = 0; v8 < 4; ++v8) {
            bf16x8 o = *(const bf16x8*)&Os[8 * v8];
            #pragma unroll
            for (int jj = 0; jj < 8; ++jj) acc[8 * v8 + jj] += as * (float)o[jj];
        }
    }

    float* dst = OUT + (size_t)bh * S * 64 + (size_t)(item * 128 + q) * 64 + 32 * half;
    #pragma unroll
    for (int v4 = 0; v4 < 8; ++v4) {
        float4 f = { acc[4*v4+0] * inv, acc[4*v4+1] * inv,
                     acc[4*v4+2] * inv, acc[4*v4+3] * inv };
        *(float4*)&dst[4 * v4] = f;
    }
}

extern "C" void kernel_launch(void* const* d_in, const int* in_sizes, int n_in,
                              void* d_out, int out_size, void* d_ws, size_t ws_size,
                              hipStream_t stream) {
    const float* q     = (const float*)d_in[0];
    const float* k     = (const float*)d_in[1];
    const float* v     = (const float*)d_in[2];
    const float* sinkw = (const float*)d_in[3];
    const int*   swin  = (const int*)d_in[4];
    float* out = (float*)d_out;

    const int H = in_sizes[3];                   // 16
    const int S = 2048;
    const int B = in_sizes[0] / (H * S * 64);    // 2
    const int NBH = B * H;                       // 32

    flex_r9_main<<<dim3(NBH * 24), NT, 0, stream>>>(q, k, v, sinkw, swin, d_ws, out, H, S);
    flex_r9_combine<<<dim3(NBH * 14), 256, 0, stream>>>(d_ws, out, H, S);
}